// Round 5
// baseline (126.517 us; speedup 1.0000x reference)
//
#include <hip/hip_runtime.h>

#define L_TOTAL 32768
#define D_MODEL 1024
#define NBLK    512                 // 2 blocks/CU needed; capacity >= 2x (deadlock-safe)
#define NTHR    512                 // 8 waves/block -> 16 waves/CU
#define LCH     128                 // l's per chunk
#define NCH     (L_TOTAL / LCH)     // 256 chunks

// Monotonic ticket barrier; zero-init at module load, never reset.
// 1024 increments/iteration; wrap handled by signed-distance compare.
__device__ unsigned int g_bar = 0u;

// Arrival: agent-scope RELEASE fetch_add (flushes this XCD's dirty L2 lines).
// Spin: RELAXED loads (NO per-iteration L2 invalidate -- R2's mistake).
// Exit: one agent-scope ACQUIRE fence (single buffer_inv), then __syncthreads.
__device__ __forceinline__ void grid_sync() {
    __syncthreads();                      // all block stores complete (vmcnt drained)
    if (threadIdx.x == 0) {
        const unsigned int ticket =
            __hip_atomic_fetch_add(&g_bar, 1u, __ATOMIC_RELEASE, __HIP_MEMORY_SCOPE_AGENT);
        const unsigned int target = (ticket & ~(unsigned int)(NBLK - 1)) + NBLK;
        while ((int)(__hip_atomic_load(&g_bar, __ATOMIC_RELAXED,
                                       __HIP_MEMORY_SCOPE_AGENT) - target) < 0)
            __builtin_amdgcn_s_sleep(2);
        __builtin_amdgcn_fence(__ATOMIC_ACQUIRE, "agent");   // one L1/L2 invalidate
    }
    __syncthreads();
}

// Single dispatch, whole problem:
//  phase 1: block (c = blk>>1, h = blk&1): part[c][d] for d = h*512+tid,
//           l in [c*128, c*128+128). Broadcast LDS loop, 4 accumulators.
//           Then PREFETCH this block's matvec W-float4 (completes during barriers).
//  barrier; phase 2 (blocks 0..255): signal[4b..4b+3] = sum_c part[c][.].
//  barrier; phase 3: rows 2*blk, 2*blk+1: dot(signal, W-row) + bias -> out.
__global__ __launch_bounds__(NTHR, 4) void fused_kernel(const float* __restrict__ x,
                                                        const float* __restrict__ W,
                                                        const float* __restrict__ b,
                                                        float* __restrict__ out,
                                                        float* __restrict__ ws) {
    __shared__ float2 sxp[LCH];          // {x[l], x[l]*log1p(l)}  1 KB
    __shared__ float  wsum[8][4];        // phase-2 cross-wave partials
    __shared__ float  rsum[8];           // phase-3 per-wave dot partials

    float* part   = ws;                  // [256][1024] partials, 1 MB
    float* signal = ws + NCH * D_MODEL;  // [1024]

    const int tid  = threadIdx.x;
    const int blk  = blockIdx.x;
    const int lane = tid & 63;
    const int wv   = tid >> 6;           // 0..7

    // ---- phase 1 ----
    const int c = blk >> 1;
    const int h = blk & 1;
    if (tid < LCH) {
        const int l = c * LCH + tid;
        const float xv = x[l];
        sxp[tid] = make_float2(xv, xv * __logf(1.0f + (float)l));
    }
    __syncthreads();

    const int   d = h * 512 + tid;
    const float t = (float)d * (1.0f / 1023.0f);   // linspace(0,1,1024)

    float a0 = 0.f, a1 = 0.f, a2 = 0.f, a3 = 0.f;
    #pragma unroll
    for (int j = 0; j < LCH; j += 4) {             // const addrs: pure broadcast
        const float2 v0 = sxp[j + 0];
        const float2 v1 = sxp[j + 1];
        const float2 v2 = sxp[j + 2];
        const float2 v3 = sxp[j + 3];
        a0 += __builtin_amdgcn_sinf(__builtin_amdgcn_fractf(fmaf(v0.x, t, v0.y)));
        a1 += __builtin_amdgcn_sinf(__builtin_amdgcn_fractf(fmaf(v1.x, t, v1.y)));
        a2 += __builtin_amdgcn_sinf(__builtin_amdgcn_fractf(fmaf(v2.x, t, v2.y)));
        a3 += __builtin_amdgcn_sinf(__builtin_amdgcn_fractf(fmaf(v3.x, t, v3.y)));
    }
    part[c * D_MODEL + d] = (a0 + a1) + (a2 + a3); // coalesced 2KB/block, no RMW

    // Prefetch this block's matvec W fragment now; 4 MB HBM total spread over
    // the barrier/spin window instead of bursting after barrier 2.
    const int   q    = wv & 3;                     // quarter-row
    const int   row  = 2 * blk + (wv >> 2);
    const float4 w4  = ((const float4*)(W + (size_t)row * D_MODEL))[q * 64 + lane];

    grid_sync();                                   // part[] globally visible

    // ---- phase 2: blocks 0..255 reduce 4 d's each ----
    if (blk < NBLK / 2) {
        const int d0 = blk * 4;
        const int di = tid & 3;
        const int c0 = tid >> 2;                   // 0..127
        float a = part[c0 * D_MODEL + d0 + di]
                + part[(c0 + 128) * D_MODEL + d0 + di];
        a += __shfl_xor(a, 4, 64);                 // reduce c within wave
        a += __shfl_xor(a, 8, 64);
        a += __shfl_xor(a, 16, 64);
        a += __shfl_xor(a, 32, 64);
        if (lane < 4) wsum[wv][lane] = a;
        __syncthreads();
        if (tid < 4)
            signal[d0 + tid] = ((wsum[0][tid] + wsum[1][tid]) +
                                (wsum[2][tid] + wsum[3][tid])) +
                               ((wsum[4][tid] + wsum[5][tid]) +
                                (wsum[6][tid] + wsum[7][tid]));
    }

    grid_sync();                                   // signal[] globally visible

    // ---- phase 3: rows 2*blk, 2*blk+1 ----
    const float4 s4 = ((const float4*)signal)[q * 64 + lane];  // coalesced, IC-hot
    float sum = w4.x * s4.x + w4.y * s4.y + w4.z * s4.z + w4.w * s4.w;
    #pragma unroll
    for (int off = 32; off > 0; off >>= 1)
        sum += __shfl_down(sum, off, 64);
    if (lane == 0) rsum[wv] = sum;
    __syncthreads();
    if (tid < 2) {
        const int r = 2 * blk + tid;
        out[r] = ((rsum[4 * tid] + rsum[4 * tid + 1]) +
                  (rsum[4 * tid + 2] + rsum[4 * tid + 3])) + b[r];
    }
}

extern "C" void kernel_launch(void* const* d_in, const int* in_sizes, int n_in,
                              void* d_out, int out_size, void* d_ws, size_t ws_size,
                              hipStream_t stream) {
    const float* x = (const float*)d_in[0];   // inputs [32768]
    const float* W = (const float*)d_in[1];   // W [1024,1024]
    const float* b = (const float*)d_in[2];   // b [1024]
    float* out    = (float*)d_out;            // [1024]
    float* ws     = (float*)d_ws;             // partials + signal (~1 MB)

    // ONE regular (graph-capturable) dispatch; no memset, no cooperative API.
    fused_kernel<<<NBLK, NTHR, 0, stream>>>(x, W, b, out, ws);
}

// Round 6
// 88.824 us; speedup vs baseline: 1.4244x; 1.4244x over previous
//
#include <hip/hip_runtime.h>

#define L_TOTAL 32768
#define D_MODEL 1024
#define NBLK    256                 // 1 block/CU; capacity >= 2x grid (deadlock-safe)
#define NTHR    1024                // 16 waves/block
#define LCH     128                 // l's per chunk (one chunk per block)
#define NCH     (L_TOTAL / LCH)     // 256 chunks
#define NLEAF   16
#define LEAF_SZ (NBLK / NLEAF)      // 16 arrivals per leaf
#define PAD     32                  // 128 B spacing between counters/flags

// Tree barrier state; zero-init at module load, monotonic, never reset.
__device__ unsigned g_leaf[NLEAF * PAD];
__device__ unsigned g_root = 0u;
__device__ unsigned g_flag[NLEAF * PAD];

// Tree barrier: 16-way leaf fetch_add (parallel lines) -> 16 root RMWs ->
// root-last broadcasts generation to 16 flag lines; blocks spin on OWN leaf flag
// with long sleep (no single-line poll storm -- R5's failure mode).
__device__ __forceinline__ void grid_sync(int leaf, unsigned gen) {
    __syncthreads();                      // block's prior stores drained
    if (threadIdx.x == 0) {
        const unsigned t = __hip_atomic_fetch_add(&g_leaf[leaf * PAD], 1u,
                                                  __ATOMIC_ACQ_REL,
                                                  __HIP_MEMORY_SCOPE_AGENT);
        if ((t & (LEAF_SZ - 1)) == (LEAF_SZ - 1)) {          // last in leaf
            const unsigned r = __hip_atomic_fetch_add(&g_root, 1u,
                                                      __ATOMIC_ACQ_REL,
                                                      __HIP_MEMORY_SCOPE_AGENT);
            if ((r & (NLEAF - 1)) == (NLEAF - 1)) {          // global last
                #pragma unroll
                for (int i = 0; i < NLEAF; ++i)
                    __hip_atomic_store(&g_flag[i * PAD], gen, __ATOMIC_RELEASE,
                                       __HIP_MEMORY_SCOPE_AGENT);
            }
        }
        while ((int)(__hip_atomic_load(&g_flag[leaf * PAD], __ATOMIC_RELAXED,
                                       __HIP_MEMORY_SCOPE_AGENT) - gen) < 0)
            __builtin_amdgcn_s_sleep(8);  // 512 cy between polls
        __builtin_amdgcn_fence(__ATOMIC_ACQUIRE, "agent");   // one L1/L2 invalidate
    }
    __syncthreads();
}

// Single dispatch:
//  phase 1: block c: part[c][d] for all 1024 d, l in [c*128, c*128+128).
//           Broadcast LDS loop, 4 accumulators. Then prefetch W fragment + bias.
//  barrier; phase 2: block b reduces signal[4b..4b+3] = sum_c part[c][.].
//  barrier; phase 3: rows 4b..4b+3: dot(signal, W-row) + bias -> out.
__global__ __launch_bounds__(NTHR, 4) void fused_kernel(const float* __restrict__ x,
                                                        const float* __restrict__ W,
                                                        const float* __restrict__ b,
                                                        float* __restrict__ out,
                                                        float* __restrict__ ws) {
    __shared__ float2 sxp[LCH];          // {x[l], x[l]*log1p(l)}  1 KB
    __shared__ float  wsum[16][4];       // phase-2 cross-wave partials
    __shared__ float  rsum[16];          // phase-3 per-wave dot partials

    float* part   = ws;                  // [256][1024] partials, 1 MB
    float* signal = ws + NCH * D_MODEL;  // [1024]

    const int tid  = threadIdx.x;
    const int blk  = blockIdx.x;
    const int lane = tid & 63;
    const int wv   = tid >> 6;           // 0..15
    const int leaf = blk & (NLEAF - 1);

    // Generation snapshot (safe: flags can't advance until every block arrives,
    // which is after every snapshot; monotonic across graph replays).
    unsigned gen0 = 0;
    if (tid == 0)
        gen0 = __hip_atomic_load(&g_flag[leaf * PAD], __ATOMIC_RELAXED,
                                 __HIP_MEMORY_SCOPE_AGENT);

    // ---- phase 1: part[blk][d] over this block's 128 l's ----
    if (tid < LCH) {
        const int l = blk * LCH + tid;
        const float xv = x[l];
        sxp[tid] = make_float2(xv, xv * __logf(1.0f + (float)l));
    }
    __syncthreads();

    const float t = (float)tid * (1.0f / 1023.0f);   // d = tid; linspace(0,1,1024)

    float a0 = 0.f, a1 = 0.f, a2 = 0.f, a3 = 0.f;
    #pragma unroll
    for (int j = 0; j < LCH; j += 4) {               // const addrs: pure broadcast
        const float2 v0 = sxp[j + 0];
        const float2 v1 = sxp[j + 1];
        const float2 v2 = sxp[j + 2];
        const float2 v3 = sxp[j + 3];
        a0 += __builtin_amdgcn_sinf(__builtin_amdgcn_fractf(fmaf(v0.x, t, v0.y)));
        a1 += __builtin_amdgcn_sinf(__builtin_amdgcn_fractf(fmaf(v1.x, t, v1.y)));
        a2 += __builtin_amdgcn_sinf(__builtin_amdgcn_fractf(fmaf(v2.x, t, v2.y)));
        a3 += __builtin_amdgcn_sinf(__builtin_amdgcn_fractf(fmaf(v3.x, t, v3.y)));
    }
    part[blk * D_MODEL + tid] = (a0 + a1) + (a2 + a3);  // coalesced 4 KB, no RMW

    // Prefetch matvec operands now: 4 MB of W spread across the barrier window.
    const int   q   = wv & 3;                        // quarter-row
    const int   rl  = wv >> 2;                       // row-local 0..3
    const float4 w4 = ((const float4*)(W + (size_t)(blk * 4 + rl) * D_MODEL))[q * 64 + lane];
    const float br  = (tid < 4) ? b[blk * 4 + tid] : 0.f;

    grid_sync(leaf, gen0 + 1);                       // part[] globally visible

    // ---- phase 2: signal[4*blk .. 4*blk+3] = sum_c part[c][.] ----
    {
        const int di = tid & 3;
        const int c0 = tid >> 2;                     // 0..255: all chunks covered
        float a = part[c0 * D_MODEL + blk * 4 + di];
        a += __shfl_xor(a, 4, 64);                   // reduce c bits within wave
        a += __shfl_xor(a, 8, 64);
        a += __shfl_xor(a, 16, 64);
        a += __shfl_xor(a, 32, 64);
        if (lane < 4) wsum[wv][lane] = a;
        __syncthreads();
        if (tid < 64) {
            float v = wsum[tid >> 2][tid & 3];
            v += __shfl_xor(v, 4, 64);               // reduce 16 waves
            v += __shfl_xor(v, 8, 64);
            v += __shfl_xor(v, 16, 64);
            v += __shfl_xor(v, 32, 64);
            if (tid < 4) signal[blk * 4 + tid] = v;
        }
    }

    grid_sync(leaf, gen0 + 2);                       // signal[] globally visible

    // ---- phase 3: out[r] = b[r] + dot(signal, W[r,:]), r = 4*blk + rl ----
    const float4 s4 = ((const float4*)signal)[q * 64 + lane];
    float sum = w4.x * s4.x + w4.y * s4.y + w4.z * s4.z + w4.w * s4.w;
    #pragma unroll
    for (int off = 32; off > 0; off >>= 1)
        sum += __shfl_down(sum, off, 64);
    if (lane == 0) rsum[wv] = sum;                   // rsum[rl*4 + q]
    __syncthreads();
    if (tid < 4)
        out[blk * 4 + tid] = ((rsum[tid * 4] + rsum[tid * 4 + 1]) +
                              (rsum[tid * 4 + 2] + rsum[tid * 4 + 3])) + br;
}

extern "C" void kernel_launch(void* const* d_in, const int* in_sizes, int n_in,
                              void* d_out, int out_size, void* d_ws, size_t ws_size,
                              hipStream_t stream) {
    const float* x = (const float*)d_in[0];   // inputs [32768]
    const float* W = (const float*)d_in[1];   // W [1024,1024]
    const float* b = (const float*)d_in[2];   // b [1024]
    float* out    = (float*)d_out;            // [1024]
    float* ws     = (float*)d_ws;             // partials + signal (~1 MB)

    // ONE regular (graph-capturable) dispatch; no memset, no cooperative API.
    fused_kernel<<<NBLK, NTHR, 0, stream>>>(x, W, b, out, ws);
}

// Round 7
// 68.747 us; speedup vs baseline: 1.8403x; 1.2920x over previous
//
#include <hip/hip_runtime.h>

#define L_TOTAL 32768
#define D_MODEL 1024
#define NCH     64                       // signal chunks
#define LCH     (L_TOTAL / NCH)          // 512 l's per chunk
#define NBLK_S  (NCH * 8)                // 512 blocks: (chunk c, d-octant q)

// K1: part[c][d] = sum_{l in chunk c} sin(2*pi*x[l]*(t[d]+log1p(l)))
// Block (c,q): 256 thr = 128 d's x 2 l-halves; per-thread 256 iters (half R4's
// serial depth), 2 blocks/CU -> 8 waves/CU. Wave-uniform LDS broadcast loop,
// 4 accumulators; halves combined in LDS; coalesced non-atomic store.
__global__ __launch_bounds__(256) void signal_kernel(const float* __restrict__ x,
                                                     float* __restrict__ part) {
    __shared__ float2 sxp[LCH];            // {x[l], x[l]*log1p(l)}  4 KB
    __shared__ float  hred[256];           // half-combine          1 KB
    const int tid = threadIdx.x;
    const int c   = blockIdx.x >> 3;       // chunk 0..63
    const int q   = blockIdx.x & 7;        // d-octant 0..7

    {   // stage 512 {x, x*log1p} pairs (2 per thread)
        const int l0 = c * LCH + tid;
        const float x0 = x[l0], x1 = x[l0 + 256];
        sxp[tid]       = make_float2(x0, x0 * __logf(1.0f + (float)l0));
        sxp[tid + 256] = make_float2(x1, x1 * __logf(1.0f + (float)(l0 + 256)));
    }
    __syncthreads();

    const int   dl = tid & 127;            // d-local
    const int   h  = tid >> 7;             // l-half 0/1 (wave-uniform)
    const float t  = (float)(q * 128 + dl) * (1.0f / 1023.0f);  // linspace(0,1,1024)

    float a0 = 0.f, a1 = 0.f, a2 = 0.f, a3 = 0.f;
    #pragma unroll 4
    for (int j = 0; j < 256; j += 4) {     // wave-uniform broadcast reads
        const float2 v0 = sxp[h * 256 + j + 0];
        const float2 v1 = sxp[h * 256 + j + 1];
        const float2 v2 = sxp[h * 256 + j + 2];
        const float2 v3 = sxp[h * 256 + j + 3];
        a0 += __builtin_amdgcn_sinf(__builtin_amdgcn_fractf(fmaf(v0.x, t, v0.y)));
        a1 += __builtin_amdgcn_sinf(__builtin_amdgcn_fractf(fmaf(v1.x, t, v1.y)));
        a2 += __builtin_amdgcn_sinf(__builtin_amdgcn_fractf(fmaf(v2.x, t, v2.y)));
        a3 += __builtin_amdgcn_sinf(__builtin_amdgcn_fractf(fmaf(v3.x, t, v3.y)));
    }
    hred[tid] = (a0 + a1) + (a2 + a3);
    __syncthreads();
    if (tid < 128)                         // combine l-halves; coalesced 512 B store
        part[c * D_MODEL + q * 128 + tid] = hred[tid] + hred[128 + tid];
}

// K2: each block reduces part (256 KB, LLC/L2-hot) -> signal in LDS, then
// matvec rows 4b..4b+3. Deletes the reduce dispatch; dispatch boundary is the sync.
__global__ __launch_bounds__(1024) void finish_kernel(const float* __restrict__ W,
                                                      const float* __restrict__ b,
                                                      const float* __restrict__ part,
                                                      float* __restrict__ out) {
    __shared__ float4 red[4][256];         // 16 KB: [c-slice][d-quad]
    __shared__ float4 ssig[256];           // signal as float4      4 KB
    __shared__ float  rsum[16];

    const int tid = threadIdx.x;
    const int blk = blockIdx.x;

    // phase A: signal[d] = sum_{c=0..63} part[c][d]; thread = (c-slice, d-quad)
    {
        const int dq = tid & 255;          // d-quad 0..255
        const int cs = tid >> 8;           // c-slice 0..3 (16 chunks each)
        const float4* p4 = (const float4*)part;   // [64][256]
        float4 A = make_float4(0.f, 0.f, 0.f, 0.f);
        float4 B = make_float4(0.f, 0.f, 0.f, 0.f);
        #pragma unroll
        for (int j = 0; j < 16; j += 2) {  // coalesced: consecutive tid -> consecutive 16B
            const float4 u = p4[(cs * 16 + j) * 256 + dq];
            const float4 v = p4[(cs * 16 + j + 1) * 256 + dq];
            A.x += u.x; A.y += u.y; A.z += u.z; A.w += u.w;
            B.x += v.x; B.y += v.y; B.z += v.z; B.w += v.w;
        }
        A.x += B.x; A.y += B.y; A.z += B.z; A.w += B.w;
        red[cs][dq] = A;
    }
    __syncthreads();
    if (tid < 256) {
        const float4 r0 = red[0][tid], r1 = red[1][tid];
        const float4 r2 = red[2][tid], r3 = red[3][tid];
        ssig[tid] = make_float4((r0.x + r1.x) + (r2.x + r3.x),
                                (r0.y + r1.y) + (r2.y + r3.y),
                                (r0.z + r1.z) + (r2.z + r3.z),
                                (r0.w + r1.w) + (r2.w + r3.w));
    }
    __syncthreads();

    // phase B: out[r] = b[r] + dot(signal, W[r,:]), r = 4*blk + rl
    const int  wv   = tid >> 6;            // 0..15
    const int  lane = tid & 63;
    const int  q    = wv & 3;              // quarter-row
    const int  rl   = wv >> 2;             // row-local 0..3
    const int  row  = blk * 4 + rl;
    const float4 w4 = ((const float4*)(W + (size_t)row * D_MODEL))[q * 64 + lane];
    const float4 s4 = ssig[q * 64 + lane];
    float sum = w4.x * s4.x + w4.y * s4.y + w4.z * s4.z + w4.w * s4.w;
    #pragma unroll
    for (int off = 32; off > 0; off >>= 1)
        sum += __shfl_down(sum, off, 64);
    if (lane == 0) rsum[wv] = sum;         // rsum[rl*4 + q]
    __syncthreads();
    if (tid < 4)
        out[blk * 4 + tid] = ((rsum[tid * 4] + rsum[tid * 4 + 1]) +
                              (rsum[tid * 4 + 2] + rsum[tid * 4 + 3])) + b[blk * 4 + tid];
}

extern "C" void kernel_launch(void* const* d_in, const int* in_sizes, int n_in,
                              void* d_out, int out_size, void* d_ws, size_t ws_size,
                              hipStream_t stream) {
    const float* x = (const float*)d_in[0];   // inputs [32768]
    const float* W = (const float*)d_in[1];   // W [1024,1024]
    const float* b = (const float*)d_in[2];   // b [1024]
    float* out    = (float*)d_out;            // [1024]
    float* part   = (float*)d_ws;             // [64][1024] partials, 256 KB

    // Two dispatches; no memset (part/out fully overwritten), no atomics, no barrier.
    signal_kernel<<<NBLK_S, 256, 0, stream>>>(x, part);
    finish_kernel<<<D_MODEL / 4, 1024, 0, stream>>>(W, b, part, out);
}